// Round 14
// baseline (156.216 us; speedup 1.0000x reference)
//
#include <hip/hip_runtime.h>
#include <hip/hip_bf16.h>
#include <stdint.h>

// Attention fwd: B=2, N=2048, D=768, H=12, Dh=64, INNER=768
// R25 = R22 (best 150.7us; attn_k/gemm_out byte-identical -- R24's cross-
// barrier kf prefetch was RACY: vmcnt only tracks own-wave DMA, kf rows are
// staged by all 4 waves, visibility needs the barrier; absmax 0.059 fail)
// + prep x-pass FUSED into gemm_qkv: A is reg-staged from f32 x directly
// (load f32 BEFORE the B DMA so the converts' in-order vmcnt wait retires
// B(it+1) while leaving B(it+2) in flight; f2bf convert; ds_write_b128 after
// the MFMA phase; lgkmcnt(0) before each barrier; explicit vmcnt(0) only at
// the it=22 tail). prep_k shrinks 2112->576 blocks (weights only), Xb slot
// becomes Ab-only.

typedef __attribute__((ext_vector_type(8))) short bf16x8;
typedef __attribute__((ext_vector_type(4))) float f32x4;
typedef __attribute__((address_space(3))) unsigned int lds_uint;
typedef __attribute__((address_space(1))) const unsigned int g_uint;

__device__ __forceinline__ short f2bf(float f) {
    union { float f; uint32_t u; } x; x.f = f;
    uint32_t r = (x.u + 0x7fffu + ((x.u >> 16) & 1u)) >> 16;
    return (short)r;
}
__device__ __forceinline__ float exp2fast(float x) {
#if __has_builtin(__builtin_amdgcn_exp2f)
    return __builtin_amdgcn_exp2f(x);
#else
    return __expf(x * 0.6931471805599453f);
#endif
}
__device__ __forceinline__ void gl_lds16(const void* g, void* l) {
    __builtin_amdgcn_global_load_lds((g_uint*)g, (lds_uint*)l, 16, 0, 0);
}
#define WAITCNT_VM(N) asm volatile("s_waitcnt vmcnt(" #N ")" ::: "memory")
#define WAITCNT_LGKM0() asm volatile("s_waitcnt lgkmcnt(0)" ::: "memory")
#define BARRIER_FENCED() do { __builtin_amdgcn_s_barrier(); \
                              asm volatile("" ::: "memory"); } while (0)

// ---------------------------------------------------------------------------
// 64x64 fp32->bf16 transpose tile (shared by prep_k / tr_w)
// ---------------------------------------------------------------------------
__device__ __forceinline__ void tr_tile(const float* __restrict__ W,
                                        short* __restrict__ Wt, int K, int N,
                                        int n0, int k0, int t, short* S) {
    {
        int kl = t >> 2, ng = t & 3;
        const float* src = W + (size_t)(k0 + kl) * N + n0 + ng * 16;
        #pragma unroll
        for (int j = 0; j < 16; j += 4) {
            float4 f = *(const float4*)(src + j);
            S[(ng*16 + j + 0) * 65 + kl] = f2bf(f.x);
            S[(ng*16 + j + 1) * 65 + kl] = f2bf(f.y);
            S[(ng*16 + j + 2) * 65 + kl] = f2bf(f.z);
            S[(ng*16 + j + 3) * 65 + kl] = f2bf(f.w);
        }
    }
    __syncthreads();
    {
        int nl = t >> 2, kg = t & 3;
        short* dst = Wt + (size_t)(n0 + nl) * K + k0 + kg * 16;
        #pragma unroll
        for (int j = 0; j < 16; j += 4) {
            short4 s4;
            s4.x = S[nl*65 + kg*16 + j + 0];
            s4.y = S[nl*65 + kg*16 + j + 1];
            s4.z = S[nl*65 + kg*16 + j + 2];
            s4.w = S[nl*65 + kg*16 + j + 3];
            *(short4*)(dst + j) = s4;
        }
    }
}

// weights-only prep: [0,432) w_qkv^T ; [432,576) w_out^T
__global__ __launch_bounds__(256)
void prep_k(const float* __restrict__ Wq, short* __restrict__ Wqt,
            const float* __restrict__ Wo, short* __restrict__ Wot)
{
    __shared__ short S[64 * 65];
    const int t = threadIdx.x;
    if (blockIdx.x < 432) {
        const int b2 = blockIdx.x;                         // N=2304, K=768
        tr_tile(Wq, Wqt, 768, 2304, (b2 % 36) * 64, (b2 / 36) * 64, t, S);
    } else {
        const int b3 = blockIdx.x - 432;                   // N=768, K=768
        tr_tile(Wo, Wot, 768, 768, (b3 % 12) * 64, (b3 / 12) * 64, t, S);
    }
}

// standalone w_out transpose (fallback when Wot must alias Wqt)
__global__ __launch_bounds__(256)
void tr_w(const float* __restrict__ W, short* __restrict__ Wt, int K, int N) {
    __shared__ short S[64 * 65];
    tr_tile(W, Wt, K, N, blockIdx.x * 64, blockIdx.y * 64, threadIdx.x, S);
}

// ---------------------------------------------------------------------------
// QKV GEMM R25: 128x96 tiles, 768 blocks = 3/CU, XCD panel remap, fully
// unrolled; B triple-buffered via gl_lds16; A reg-staged DIRECTLY FROM f32 x
// (fused bf16 conversion -- eliminates prep's x pass). Per round:
//   [A f32 loads(it+2)] [B DMA(it+2)] [MFMA on tile it] [convert+ds_write A]
//   [lgkmcnt(0)] [barrier]   (vmcnt(0) only at it=22 tail)
// In-order vmcnt: converts' implicit wait on A(it+2) retires B(it+1) (issued
// earlier) while leaving B(it+2) (issued after A) in flight across barriers.
// ds_write target (it+2)%3 was read in round it-1, fenced by that barrier.
// [4096x768]f32 @ Wqt[2304x768]^T + b -> Qb(pre-scaled)/Kb/Vt bf16
// ---------------------------------------------------------------------------
#define QKV_WRITE_A(BUF, F00, F01, F10, F11) do {                              \
    short s0[8];                                                               \
    s0[0]=f2bf(F00.x); s0[1]=f2bf(F00.y); s0[2]=f2bf(F00.z); s0[3]=f2bf(F00.w);\
    s0[4]=f2bf(F01.x); s0[5]=f2bf(F01.y); s0[6]=f2bf(F01.z); s0[7]=f2bf(F01.w);\
    *(uint4*)(As[BUF] + tid * 8) = *(uint4*)s0;                                \
    short s1[8];                                                               \
    s1[0]=f2bf(F10.x); s1[1]=f2bf(F10.y); s1[2]=f2bf(F10.z); s1[3]=f2bf(F10.w);\
    s1[4]=f2bf(F11.x); s1[5]=f2bf(F11.y); s1[6]=f2bf(F11.z); s1[7]=f2bf(F11.w);\
    *(uint4*)(As[BUF] + (tid + 256) * 8) = *(uint4*)s1;                        \
} while (0)

__global__ __launch_bounds__(256)
void gemm_qkv(const float* __restrict__ X, const short* __restrict__ Bt,
              const float* __restrict__ bias,
              short* __restrict__ Qb, short* __restrict__ Kb, short* __restrict__ Vt)
{
    __shared__ short As[3][128 * 32];  // 8KB per buffer
    __shared__ short Bs[3][96 * 32];   // 6KB per buffer (42KB total)
    const int tid = threadIdx.x, lane = tid & 63, w = tid >> 6;
    const int wm = w >> 1, wn = w & 1, quad = lane >> 4, lcol = lane & 15;

    // XCD-panel-grouped remap (bijective: 768 = 8 XCD * 4 bm * 24 bn)
    const int id = blockIdx.x;
    const int xcd = id & 7, j = id >> 3;
    const int bm = (xcd * 4 + (j / 24)) * 128;
    const int bn = (j % 24) * 96;

    f32x4 acc[4][3];
    #pragma unroll
    for (int i = 0; i < 4; i++)
        #pragma unroll
        for (int jj = 0; jj < 3; jj++) acc[i][jj] = (f32x4){0.f, 0.f, 0.f, 0.f};

    const int ar0 = tid >> 2,         ac0 = (tid & 3) * 8;
    const int ar1 = (tid + 256) >> 2;
    const int c2  = 256 + tid;         // only tid<128 uses it
    const int br1 = c2 >> 2,          bc1 = (c2 & 3) * 8;

    const float* pX0 = X  + (size_t)(bm + ar0) * 768 + ac0;
    const float* pX1 = X  + (size_t)(bm + ar1) * 768 + ac0;
    const short* pB0 = Bt + (size_t)(bn + ar0) * 768 + ac0;
    const short* pB1 = Bt + (size_t)(bn + br1) * 768 + bc1;

    // prologue: stage tiles 0,1 (A loads BEFORE B DMA per tile)
    float4 a00 = *(const float4*)(pX0 + 0),  a01 = *(const float4*)(pX0 + 4);
    float4 a10 = *(const float4*)(pX1 + 0),  a11 = *(const float4*)(pX1 + 4);
    gl_lds16(pB0 + 0, Bs[0] + tid * 8);
    if (tid < 128) gl_lds16(pB1 + 0, Bs[0] + c2 * 8);
    float4 b00 = *(const float4*)(pX0 + 32), b01 = *(const float4*)(pX0 + 36);
    float4 b10 = *(const float4*)(pX1 + 32), b11 = *(const float4*)(pX1 + 36);
    gl_lds16(pB0 + 32, Bs[1] + tid * 8);
    if (tid < 128) gl_lds16(pB1 + 32, Bs[1] + c2 * 8);
    QKV_WRITE_A(0, a00, a01, a10, a11);    // waits A(0) -> retires B(0) too? no:
    QKV_WRITE_A(1, b00, b01, b10, b11);    // waits A(1) -> retires B(0); B(1) stays
    WAITCNT_LGKM0();
    BARRIER_FENCED();

    #pragma unroll
    for (int it = 0; it < 24; it++) {
        const int p = it % 3;
        float4 c00, c01, c10, c11;
        if (it < 22) {                 // A loads first, then B DMA (in-order trick)
            const int kt = (it + 2) * 32;
            c00 = *(const float4*)(pX0 + kt); c01 = *(const float4*)(pX0 + kt + 4);
            c10 = *(const float4*)(pX1 + kt); c11 = *(const float4*)(pX1 + kt + 4);
            gl_lds16(pB0 + kt, Bs[(it + 2) % 3] + tid * 8);
            if (tid < 128) gl_lds16(pB1 + kt, Bs[(it + 2) % 3] + c2 * 8);
        }
        bf16x8 a[4], b[3];
        #pragma unroll
        for (int tm = 0; tm < 4; tm++)
            a[tm] = *(const bf16x8*)(As[p] + (wm*64 + tm*16 + lcol) * 32 + quad * 8);
        #pragma unroll
        for (int tn = 0; tn < 3; tn++)
            b[tn] = *(const bf16x8*)(Bs[p] + (wn*48 + tn*16 + lcol) * 32 + quad * 8);
        #pragma unroll
        for (int tm = 0; tm < 4; tm++)
            #pragma unroll
            for (int tn = 0; tn < 3; tn++)
                acc[tm][tn] = __builtin_amdgcn_mfma_f32_16x16x32_bf16(a[tm], b[tn], acc[tm][tn], 0, 0, 0);
        if (it < 22)                   // convert+write AFTER MFMA (hide A latency)
            QKV_WRITE_A((it + 2) % 3, c00, c01, c10, c11);
        if (it < 23) {
            WAITCNT_LGKM0();           // ds_writes drained before publish
            if (it == 22) WAITCNT_VM(0);   // tail: drain B(23) (no A-wait after 21)
            BARRIER_FENCED();
        }
    }

    const float SCLQ = 0.18033688011112042f;   // 0.125 * log2(e) folded into Q
    #pragma unroll
    for (int tm = 0; tm < 4; tm++) {
        #pragma unroll
        for (int tn = 0; tn < 3; tn++) {
            int col = bn + wn*48 + tn*16 + lcol;
            float bv = bias[col];
            int which = (col >= 1536) ? 2 : (col >= 768 ? 1 : 0);
            int cc = col - which * 768;
            int h = cc >> 6, d = cc & 63;
            int rowbase = bm + wm*64 + tm*16 + quad*4;
            int bb = rowbase >> 11, n0 = rowbase & 2047;
            int bh = bb * 12 + h;
            if (which == 2) {                 // V: tiled V^T store, dense window
                short4 s4;
                s4.x = f2bf(acc[tm][tn][0] + bv);
                s4.y = f2bf(acc[tm][tn][1] + bv);
                s4.z = f2bf(acc[tm][tn][2] + bv);
                s4.w = f2bf(acc[tm][tn][3] + bv);
                *(short4*)(Vt + (((size_t)bh*32 + (n0 >> 6))*64 + d)*64 + (n0 & 63)) = s4;
            } else {
                #pragma unroll
                for (int reg = 0; reg < 4; reg++) {
                    float v = acc[tm][tn][reg] + bv;
                    if (which == 0) v *= SCLQ;
                    short* dst = (which == 0) ? Qb : Kb;
                    dst[((size_t)bh*2048 + n0 + reg)*64 + d] = f2bf(v);
                }
            }
        }
    }
}

// ---------------------------------------------------------------------------
// Flash attention R25 = R22 (best measured): R15 compute, compile-time
// buffer rotation via 10x3 macro-unrolled steps, 4 running DMA pointers.
// WMODE: 0 = vmcnt(4)+barrier (steady), 1 = vmcnt(0)+barrier, 2 = none.
// ---------------------------------------------------------------------------
#define ATTN_STEP(P, PB, DO_PRE, WMODE) do {                                   \
    if (DO_PRE) {                                                              \
        gl_lds16(pK0, Ks[PB] + c0 * 8);                                        \
        gl_lds16(pV0, Vs[PB] + c0 * 8);                                        \
        gl_lds16(pK1, Ks[PB] + c1 * 8);                                        \
        gl_lds16(pV1, Vs[PB] + c1 * 8);                                        \
        pK0 += 4096; pV0 += 4096; pK1 += 4096; pV1 += 4096;                    \
    }                                                                          \
    f32x4 st[4];                                                               \
    _Pragma("unroll")                                                          \
    for (int kvs = 0; kvs < 4; kvs++) st[kvs] = (f32x4){0.f, 0.f, 0.f, 0.f};   \
    _Pragma("unroll")                                                          \
    for (int ks = 0; ks < 2; ks++) {                                           \
        _Pragma("unroll")                                                      \
        for (int kvs = 0; kvs < 4; kvs++) {                                    \
            bf16x8 kf = *(const bf16x8*)(Ks[P] + (kvs*16 + lcol) * 64 +        \
                                         (((ks*4 + quad) ^ ksw) << 3));        \
            st[kvs] = __builtin_amdgcn_mfma_f32_16x16x32_bf16(kf, qf[ks],      \
                                                              st[kvs], 0, 0, 0); \
        }                                                                      \
    }                                                                          \
    uint32_t X[4], Y[4];                                                       \
    _Pragma("unroll")                                                          \
    for (int kvs = 0; kvs < 4; kvs++) {                                        \
        float p0 = exp2fast(st[kvs][0]), p1 = exp2fast(st[kvs][1]);            \
        float p2 = exp2fast(st[kvs][2]), p3 = exp2fast(st[kvs][3]);            \
        lp += (p0 + p1) + (p2 + p3);                                           \
        asm("v_cvt_pk_bf16_f32 %0, %1, %2" : "=v"(X[kvs]) : "v"(p0), "v"(p1)); \
        asm("v_cvt_pk_bf16_f32 %0, %1, %2" : "=v"(Y[kvs]) : "v"(p2), "v"(p3)); \
    }                                                                          \
    bf16x8 pa[2];                                                              \
    _Pragma("unroll")                                                          \
    for (int ks = 0; ks < 2; ks++) {                                           \
        uint32_t a0 = X[2*ks], a1 = X[2*ks + 1];                               \
        uint32_t b0 = Y[2*ks], b1 = Y[2*ks + 1];                               \
        asm("v_permlane16_swap_b32 %0, %1" : "+v"(a0), "+v"(a1));              \
        asm("v_permlane16_swap_b32 %0, %1" : "+v"(b0), "+v"(b1));              \
        union { uint32_t u[4]; bf16x8 v; } pk_;                                \
        pk_.u[0] = a0; pk_.u[1] = b0; pk_.u[2] = a1; pk_.u[3] = b1;            \
        pa[ks] = pk_.v;                                                        \
    }                                                                          \
    _Pragma("unroll")                                                          \
    for (int ks = 0; ks < 2; ks++) {                                           \
        _Pragma("unroll")                                                      \
        for (int tn = 0; tn < 4; tn++) {                                       \
            int row = tn * 16 + lcol;                                          \
            bf16x8 bv = *(const bf16x8*)(Vs[P] + row * 64 +                    \
                                         (((ks*4 + bq) ^ (row & 7)) << 3));    \
            o[tn] = __builtin_amdgcn_mfma_f32_16x16x32_bf16(pa[ks], bv,        \
                                                            o[tn], 0, 0, 0);   \
        }                                                                      \
    }                                                                          \
    if (WMODE == 0) { WAITCNT_VM(4); BARRIER_FENCED(); }                       \
    else if (WMODE == 1) { WAITCNT_VM(0); BARRIER_FENCED(); }                  \
} while (0)

__global__ __launch_bounds__(256)
void attn_k(const short* __restrict__ Q, const short* __restrict__ K,
            const short* __restrict__ Vt, short* __restrict__ Ab)
{
    __shared__ __align__(16) short Ks[3][4096];   // [kv][d] xor-swizzled chunks
    __shared__ __align__(16) short Vs[3][4096];   // [d][kv] xor-swizzled chunks

    const int tid = threadIdx.x, lane = tid & 63, w = tid >> 6;
    const int quad = lane >> 4, lcol = lane & 15;
    const int bid = blockIdx.x;
    const int bh = bid % 24, qt = bid / 24;
    const int b = bh / 12, h = bh - b * 12;

    const short* Kg = K  + (size_t)bh * 131072;   // [n][d] rows, tile = 8KB
    const short* Vg = Vt + (size_t)bh * 131072;   // tiled [kt][d][n64], 8KB

    bf16x8 qf[2];                       // this wave's 16 q rows only
    {
        const short* Qg = Q + ((size_t)bh * 2048 + (size_t)qt * 64) * 64;
        #pragma unroll
        for (int ks = 0; ks < 2; ks++)
            qf[ks] = *(const bf16x8*)(Qg + (w*16 + lcol) * 64 + ks*32 + quad*8);
    }

    // per-thread chunk mapping (c0: chunks 0..511, c1: 512..1023 of each tile)
    const int c0 = tid, c1 = tid + 256;
    const int r0 = c0 >> 3, s0 = r0 * 64 + (((c0 & 7) ^ (r0 & 7)) << 3);
    const int r1 = c1 >> 3, s1 = r1 * 64 + (((c1 & 7) ^ (r1 & 7)) << 3);

    // stage tiles 0,1 (4 loads/thread/tile, uniform)
    #pragma unroll
    for (int t0 = 0; t0 < 2; t0++) {
        gl_lds16(Kg + t0 * 4096 + s0, Ks[t0] + c0 * 8);
        gl_lds16(Vg + t0 * 4096 + s0, Vs[t0] + c0 * 8);
        gl_lds16(Kg + t0 * 4096 + s1, Ks[t0] + c1 * 8);
        gl_lds16(Vg + t0 * 4096 + s1, Vs[t0] + c1 * 8);
    }
    WAITCNT_VM(4);                     // Q loads + tile 0 landed; tile 1 in flight
    BARRIER_FENCED();

    // running prefetch source pointers (tile kt+2), advance 1 tile per step
    const short* pK0 = Kg + 2 * 4096 + s0;
    const short* pV0 = Vg + 2 * 4096 + s0;
    const short* pK1 = Kg + 2 * 4096 + s1;
    const short* pV1 = Vg + 2 * 4096 + s1;

    f32x4 o[4];
    #pragma unroll
    for (int tn = 0; tn < 4; tn++) o[tn] = (f32x4){0.f, 0.f, 0.f, 0.f};
    float lp = 0.f;

    const int ksw = lcol & 7;                       // K row-xor ((kvs*16+lcol)&7)
    const int bq  = ((quad & 1) << 1) | (quad >> 1); // V chunk bit-reverse perm

    for (int g = 0; g < 10; g++) {      // kt = 3g+0, 3g+1, 3g+2  (0..29)
        ATTN_STEP(0, 2, true, 0);
        ATTN_STEP(1, 0, true, 0);
        ATTN_STEP(2, 1, true, 0);
    }
    ATTN_STEP(0, 0, false, 1);          // kt = 30: drain tile 31
    ATTN_STEP(1, 0, false, 2);          // kt = 31: last, no barrier

    // row-sum: kv-split is across quads of the SAME wave -> pure shuffles
    lp += __shfl_xor(lp, 16, 64);
    lp += __shfl_xor(lp, 32, 64);
    float rl[4];
    #pragma unroll
    for (int r = 0; r < 4; r++)
        rl[r] = 1.0f / __shfl(lp, quad * 4 + r, 64);   // lane lcol=q' holds sum(q')

    #pragma unroll
    for (int tn = 0; tn < 4; tn++) {
        #pragma unroll
        for (int r = 0; r < 4; r++) {
            int q = qt * 64 + w * 16 + quad * 4 + r;
            int d = h * 64 + tn * 16 + lcol;
            Ab[((size_t)(b * 2048 + q)) * 768 + d] = f2bf(o[tn][r] * rl[r]);
        }
    }
}

// ---------------------------------------------------------------------------
// out-proj GEMM R25 = R22: 64x96 tiles, 512 blocks = 2/CU (grid-capped),
// XCD panel remap, 5-buffer / distance-3 / barrier-every-2, counted vmcnt.
// ---------------------------------------------------------------------------
__global__ __launch_bounds__(256)
void gemm_out(const short* __restrict__ A, const short* __restrict__ Bt,
              const float* __restrict__ bias, float* __restrict__ Of)
{
    __shared__ short As[5][64 * 32];   // 4KB per buffer (20KB)
    __shared__ short Bs[5][96 * 32];   // 6KB per buffer (30KB)
    const int tid = threadIdx.x, lane = tid & 63, w = tid >> 6;
    const int wm = w >> 1, wn = w & 1, quad = lane >> 4, lcol = lane & 15;

    // XCD-panel-grouped remap (bijective: 512 = 8 XCD * 8 bm * 8 bn)
    const int id = blockIdx.x;
    const int xcd = id & 7, j = id >> 3;
    const int bm = (xcd * 8 + (j >> 3)) * 64;
    const int bn = (j & 7) * 96;

    f32x4 acc[2][3];
    #pragma unroll
    for (int i = 0; i < 2; i++)
        #pragma unroll
        for (int jj = 0; jj < 3; jj++) acc[i][jj] = (f32x4){0.f, 0.f, 0.f, 0.f};

    const int ar0 = tid >> 2, ac0 = (tid & 3) * 8;
    const int c2  = 256 + tid;         // only tid<128 uses it
    const int br1 = c2 >> 2,  bc1 = (c2 & 3) * 8;

    const short* pA0 = A  + (size_t)(bm + ar0) * 768 + ac0;
    const short* pB0 = Bt + (size_t)(bn + ar0) * 768 + ac0;
    const short* pB1 = Bt + (size_t)(bn + br1) * 768 + bc1;

    #pragma unroll
    for (int t0 = 0; t0 < 3; t0++) {   // stage tiles 0,1,2
        const int kt = t0 * 32;
        gl_lds16(pA0 + kt, As[t0] + tid * 8);
        gl_lds16(pB0 + kt, Bs[t0] + tid * 8);
        if (tid < 128)
            gl_lds16(pB1 + kt, Bs[t0] + c2 * 8);
    }
    if (w < 2) { WAITCNT_VM(3); } else { WAITCNT_VM(2); }   // 0,1 landed; 2 in flight
    BARRIER_FENCED();

    #pragma unroll
    for (int it = 0; it < 24; it++) {
        const int p = it % 5;
        if (it < 21) {                 // prefetch tile it+3 (constants after unroll)
            const int pb = (it + 3) % 5, kt = (it + 3) * 32;
            gl_lds16(pA0 + kt, As[pb] + tid * 8);
            gl_lds16(pB0 + kt, Bs[pb] + tid * 8);
            if (tid < 128)
                gl_lds16(pB1 + kt, Bs[pb] + c2 * 8);
        }
        bf16x8 a[2], b[3];
        #pragma unroll
        for (int tm = 0; tm < 2; tm++)
            a[tm] = *(const bf16x8*)(As[p] + (wm*32 + tm*16 + lcol) * 32 + quad * 8);
        #pragma unroll
        for (int tn = 0; tn < 3; tn++)
            b[tn] = *(const bf16x8*)(Bs[p] + (wn*48 + tn*16 + lcol) * 32 + quad * 8);
        #pragma unroll
        for (int tm = 0; tm < 2; tm++)
            #pragma unroll
            for (int tn = 0; tn < 3; tn++)
                acc[tm][tn] = __builtin_amdgcn_mfma_f32_16x16x32_bf16(a[tm], b[tn], acc[tm][tn], 0, 0, 0);
        if ((it & 1) && it <= 21) {    // barrier every 2 rounds
            if (it < 21) {
                if (w < 2) { WAITCNT_VM(3); } else { WAITCNT_VM(2); }
            } else {
                WAITCNT_VM(0);         // it=21: drain tail (tiles 22,23 staged)
            }
            BARRIER_FENCED();
        }
    }
    #pragma unroll
    for (int tm = 0; tm < 2; tm++) {
        #pragma unroll
        for (int tn = 0; tn < 3; tn++) {
            int col = bn + wn*48 + tn*16 + lcol;
            float bv = bias[col];
            #pragma unroll
            for (int reg = 0; reg < 4; reg++) {
                int row = bm + wm*32 + tm*16 + quad*4 + reg;
                Of[(size_t)row * 768 + col] = acc[tm][tn][reg] + bv;
            }
        }
    }
}

// ---------------------------------------------------------------------------
extern "C" void kernel_launch(void* const* d_in, const int* in_sizes, int n_in,
                              void* d_out, int out_size, void* d_ws, size_t ws_size,
                              hipStream_t stream)
{
    (void)in_sizes; (void)n_in; (void)out_size;
    const float* x     = (const float*)d_in[0];
    const float* w_qkv = (const float*)d_in[1];
    const float* b_qkv = (const float*)d_in[2];
    const float* w_out = (const float*)d_in[3];
    const float* b_out = (const float*)d_in[4];
    float* out = (float*)d_out;

    const size_t ABZ = (size_t)4096 * 768;     // Ab (attn output), was Xb slot
    const size_t WQ  = (size_t)2304 * 768;
    const size_t WO  = (size_t)768 * 768;
    const size_t HSZ = (size_t)24 * 2048 * 64;
    short* Ab  = (short*)d_ws;
    short* Wqt = Ab + ABZ;
    short* Qb  = Wqt + WQ;
    short* Kb  = Qb + HSZ;
    short* Vt  = Kb + HSZ;

    const bool sepWot = ws_size >= (ABZ + WQ + 3*HSZ + WO) * sizeof(short);
    short* Wot = sepWot ? (Vt + HSZ) : Wqt;   // else alias (w_qkv^T dead after gemm0)

    if (sepWot) {
        prep_k<<<576, 256, 0, stream>>>(w_qkv, Wqt, w_out, Wot);
        gemm_qkv<<<768, 256, 0, stream>>>(x, Wqt, b_qkv, Qb, Kb, Vt);
    } else {
        prep_k<<<432, 256, 0, stream>>>(w_qkv, Wqt, w_out, Wot);
        gemm_qkv<<<768, 256, 0, stream>>>(x, Wqt, b_qkv, Qb, Kb, Vt);
        tr_w<<<dim3(12, 12), 256, 0, stream>>>(w_out, Wot, 768, 768);
    }
    attn_k<<<768, 256, 0, stream>>>(Qb, Kb, Vt, Ab);
    gemm_out<<<512, 256, 0, stream>>>(Ab, Wot, b_out, out);
}

// Round 18
// 153.545 us; speedup vs baseline: 1.0174x; 1.0174x over previous
//
#include <hip/hip_runtime.h>
#include <hip/hip_bf16.h>
#include <stdint.h>

// Attention fwd: B=2, N=2048, D=768, H=12, Dh=64, INNER=768
// R29 = R22 byte-exact (measured best 150.7us). Locking in the optimum:
//  * R23 wave-split gemms: regressed (+2.0) -- reverted.
//  * R24 cross-barrier kf prefetch: RACY (vmcnt tracks own-wave DMA only;
//    kf rows staged by all 4 waves need the barrier for visibility).
//  * R25 prep-fusion into qkv: regressed (+5.5) -- fused A loads get only
//    intra-round cover + lgkmcnt(0) re-serializes the counted-vmcnt loop.
// Structure: attn = R18-form (compile-time 3-buffer rotation, counted
// vmcnt(4), in-register P transpose); gemm_qkv = R19-form (128x96, 3/CU
// grid- and LDS-matched, 3-buffer counted vmcnt, XCD panel remap);
// gemm_out = 5-buffer / distance-3 / barrier-every-2 (R22's win).
// (3rd resubmission -- R26/R27/R28 all hit GPUAcquisitionTimeout, never ran.)

typedef __attribute__((ext_vector_type(8))) short bf16x8;
typedef __attribute__((ext_vector_type(4))) float f32x4;
typedef __attribute__((address_space(3))) unsigned int lds_uint;
typedef __attribute__((address_space(1))) const unsigned int g_uint;

__device__ __forceinline__ short f2bf(float f) {
    union { float f; uint32_t u; } x; x.f = f;
    uint32_t r = (x.u + 0x7fffu + ((x.u >> 16) & 1u)) >> 16;
    return (short)r;
}
__device__ __forceinline__ float exp2fast(float x) {
#if __has_builtin(__builtin_amdgcn_exp2f)
    return __builtin_amdgcn_exp2f(x);
#else
    return __expf(x * 0.6931471805599453f);
#endif
}
__device__ __forceinline__ void gl_lds16(const void* g, void* l) {
    __builtin_amdgcn_global_load_lds((g_uint*)g, (lds_uint*)l, 16, 0, 0);
}
#define WAITCNT_VM(N) asm volatile("s_waitcnt vmcnt(" #N ")" ::: "memory")
#define BARRIER_FENCED() do { __builtin_amdgcn_s_barrier(); \
                              asm volatile("" ::: "memory"); } while (0)

// ---------------------------------------------------------------------------
// 64x64 fp32->bf16 transpose tile (shared by prep_k / tr_w)
// ---------------------------------------------------------------------------
__device__ __forceinline__ void tr_tile(const float* __restrict__ W,
                                        short* __restrict__ Wt, int K, int N,
                                        int n0, int k0, int t, short* S) {
    {
        int kl = t >> 2, ng = t & 3;
        const float* src = W + (size_t)(k0 + kl) * N + n0 + ng * 16;
        #pragma unroll
        for (int j = 0; j < 16; j += 4) {
            float4 f = *(const float4*)(src + j);
            S[(ng*16 + j + 0) * 65 + kl] = f2bf(f.x);
            S[(ng*16 + j + 1) * 65 + kl] = f2bf(f.y);
            S[(ng*16 + j + 2) * 65 + kl] = f2bf(f.z);
            S[(ng*16 + j + 3) * 65 + kl] = f2bf(f.w);
        }
    }
    __syncthreads();
    {
        int nl = t >> 2, kg = t & 3;
        short* dst = Wt + (size_t)(n0 + nl) * K + k0 + kg * 16;
        #pragma unroll
        for (int j = 0; j < 16; j += 4) {
            short4 s4;
            s4.x = S[nl*65 + kg*16 + j + 0];
            s4.y = S[nl*65 + kg*16 + j + 1];
            s4.z = S[nl*65 + kg*16 + j + 2];
            s4.w = S[nl*65 + kg*16 + j + 3];
            *(short4*)(dst + j) = s4;
        }
    }
}

// fused prep: [0,1536) x->bf16 ; [1536,1968) w_qkv^T ; [1968,2112) w_out^T
__global__ __launch_bounds__(256)
void prep_k(const float* __restrict__ x, short* __restrict__ Xb,
            const float* __restrict__ Wq, short* __restrict__ Wqt,
            const float* __restrict__ Wo, short* __restrict__ Wot)
{
    __shared__ short S[64 * 65];
    const int t = threadIdx.x;
    if (blockIdx.x < 1536) {
        int i = (blockIdx.x * 256 + t) * 8;
        float4 f0 = *(const float4*)(x + i);
        float4 f1 = *(const float4*)(x + i + 4);
        short s[8];
        s[0]=f2bf(f0.x); s[1]=f2bf(f0.y); s[2]=f2bf(f0.z); s[3]=f2bf(f0.w);
        s[4]=f2bf(f1.x); s[5]=f2bf(f1.y); s[6]=f2bf(f1.z); s[7]=f2bf(f1.w);
        *(uint4*)(Xb + i) = *(uint4*)s;
        return;
    }
    if (blockIdx.x < 1968) {
        const int b2 = blockIdx.x - 1536;                  // N=2304, K=768
        tr_tile(Wq, Wqt, 768, 2304, (b2 % 36) * 64, (b2 / 36) * 64, t, S);
    } else {
        const int b3 = blockIdx.x - 1968;                  // N=768, K=768
        tr_tile(Wo, Wot, 768, 768, (b3 % 12) * 64, (b3 / 12) * 64, t, S);
    }
}

// standalone w_out transpose (fallback when Wot must alias Wqt)
__global__ __launch_bounds__(256)
void tr_w(const float* __restrict__ W, short* __restrict__ Wt, int K, int N) {
    __shared__ short S[64 * 65];
    tr_tile(W, Wt, K, N, blockIdx.x * 64, blockIdx.y * 64, threadIdx.x, S);
}

// ---------------------------------------------------------------------------
// QKV GEMM: 128x96 tiles, 768 blocks = 3/CU, triple-buffered counted-vmcnt
// staging, fully unrolled K-loop, XCD panel remap
// (768 = 8 xcd x 4 bm x 24 bn; per-XCD A 0.77MB + B 3.5MB, L2-resident).
// [4096x768]bf16 @ Wqt[2304x768]^T + b -> Qb(pre-scaled)/Kb/Vt bf16
// ---------------------------------------------------------------------------
__global__ __launch_bounds__(256)
void gemm_qkv(const short* __restrict__ A, const short* __restrict__ Bt,
              const float* __restrict__ bias,
              short* __restrict__ Qb, short* __restrict__ Kb, short* __restrict__ Vt)
{
    __shared__ short As[3][128 * 32];  // 512 chunks of 16B per buffer (24KB)
    __shared__ short Bs[3][96 * 32];   // 384 chunks per buffer (18KB)
    const int tid = threadIdx.x, lane = tid & 63, w = tid >> 6;
    const int wm = w >> 1, wn = w & 1, quad = lane >> 4, lcol = lane & 15;

    // XCD-panel-grouped remap (bijective: 768 = 8 XCD * 4 bm * 24 bn)
    const int id = blockIdx.x;
    const int xcd = id & 7, j = id >> 3;
    const int bm = (xcd * 4 + (j / 24)) * 128;
    const int bn = (j % 24) * 96;

    f32x4 acc[4][3];
    #pragma unroll
    for (int i = 0; i < 4; i++)
        #pragma unroll
        for (int jj = 0; jj < 3; jj++) acc[i][jj] = (f32x4){0.f, 0.f, 0.f, 0.f};

    const int ar0 = tid >> 2,         ac0 = (tid & 3) * 8;
    const int ar1 = (tid + 256) >> 2;
    const int c2  = 256 + tid;         // only tid<128 uses it
    const int br1 = c2 >> 2,          bc1 = (c2 & 3) * 8;

    const short* pA0 = A  + (size_t)(bm + ar0) * 768 + ac0;
    const short* pA1 = A  + (size_t)(bm + ar1) * 768 + ac0;
    const short* pB0 = Bt + (size_t)(bn + ar0) * 768 + ac0;
    const short* pB1 = Bt + (size_t)(bn + br1) * 768 + bc1;

    #pragma unroll
    for (int t0 = 0; t0 < 2; t0++) {   // stage tiles 0,1
        const int kt = t0 * 32;
        gl_lds16(pA0 + kt, As[t0] + tid * 8);
        gl_lds16(pA1 + kt, As[t0] + (tid + 256) * 8);
        gl_lds16(pB0 + kt, Bs[t0] + tid * 8);
        if (tid < 128)
            gl_lds16(pB1 + kt, Bs[t0] + c2 * 8);
    }
    if (w < 2) { WAITCNT_VM(4); } else { WAITCNT_VM(3); }   // tile0 done, tile1 in flight
    BARRIER_FENCED();

    #pragma unroll
    for (int it = 0; it < 24; it++) {
        const int p = it % 3;
        if (it < 22) {                 // prefetch tile it+2 (constants after unroll)
            const int pb = (it + 2) % 3, kt = (it + 2) * 32;
            gl_lds16(pA0 + kt, As[pb] + tid * 8);
            gl_lds16(pA1 + kt, As[pb] + (tid + 256) * 8);
            gl_lds16(pB0 + kt, Bs[pb] + tid * 8);
            if (tid < 128)
                gl_lds16(pB1 + kt, Bs[pb] + c2 * 8);
        }
        bf16x8 a[4], b[3];
        #pragma unroll
        for (int tm = 0; tm < 4; tm++)
            a[tm] = *(const bf16x8*)(As[p] + (wm*64 + tm*16 + lcol) * 32 + quad * 8);
        #pragma unroll
        for (int tn = 0; tn < 3; tn++)
            b[tn] = *(const bf16x8*)(Bs[p] + (wn*48 + tn*16 + lcol) * 32 + quad * 8);
        #pragma unroll
        for (int tm = 0; tm < 4; tm++)
            #pragma unroll
            for (int tn = 0; tn < 3; tn++)
                acc[tm][tn] = __builtin_amdgcn_mfma_f32_16x16x32_bf16(a[tm], b[tn], acc[tm][tn], 0, 0, 0);
        if (it < 23) {
            if (it < 22) {             // tile it+1 landed, it+2 stays in flight
                if (w < 2) { WAITCNT_VM(4); } else { WAITCNT_VM(3); }
            } else {
                WAITCNT_VM(0);         // drain last staged tile
            }
            BARRIER_FENCED();
        }
    }

    const float SCLQ = 0.18033688011112042f;   // 0.125 * log2(e) folded into Q
    #pragma unroll
    for (int tm = 0; tm < 4; tm++) {
        #pragma unroll
        for (int tn = 0; tn < 3; tn++) {
            int col = bn + wn*48 + tn*16 + lcol;
            float bv = bias[col];
            int which = (col >= 1536) ? 2 : (col >= 768 ? 1 : 0);
            int cc = col - which * 768;
            int h = cc >> 6, d = cc & 63;
            int rowbase = bm + wm*64 + tm*16 + quad*4;
            int bb = rowbase >> 11, n0 = rowbase & 2047;
            int bh = bb * 12 + h;
            if (which == 2) {                 // V: tiled V^T store, dense window
                short4 s4;
                s4.x = f2bf(acc[tm][tn][0] + bv);
                s4.y = f2bf(acc[tm][tn][1] + bv);
                s4.z = f2bf(acc[tm][tn][2] + bv);
                s4.w = f2bf(acc[tm][tn][3] + bv);
                *(short4*)(Vt + (((size_t)bh*32 + (n0 >> 6))*64 + d)*64 + (n0 & 63)) = s4;
            } else {
                #pragma unroll
                for (int reg = 0; reg < 4; reg++) {
                    float v = acc[tm][tn][reg] + bv;
                    if (which == 0) v *= SCLQ;
                    short* dst = (which == 0) ? Qb : Kb;
                    dst[((size_t)bh*2048 + n0 + reg)*64 + d] = f2bf(v);
                }
            }
        }
    }
}

// ---------------------------------------------------------------------------
// Flash attention: R15 compute, compile-time buffer rotation via 10x3
// macro-unrolled steps, 4 running DMA pointers.
// WMODE: 0 = vmcnt(4)+barrier (steady), 1 = vmcnt(0)+barrier, 2 = none.
// ---------------------------------------------------------------------------
#define ATTN_STEP(P, PB, DO_PRE, WMODE) do {                                   \
    if (DO_PRE) {                                                              \
        gl_lds16(pK0, Ks[PB] + c0 * 8);                                        \
        gl_lds16(pV0, Vs[PB] + c0 * 8);                                        \
        gl_lds16(pK1, Ks[PB] + c1 * 8);                                        \
        gl_lds16(pV1, Vs[PB] + c1 * 8);                                        \
        pK0 += 4096; pV0 += 4096; pK1 += 4096; pV1 += 4096;                    \
    }                                                                          \
    f32x4 st[4];                                                               \
    _Pragma("unroll")                                                          \
    for (int kvs = 0; kvs < 4; kvs++) st[kvs] = (f32x4){0.f, 0.f, 0.f, 0.f};   \
    _Pragma("unroll")                                                          \
    for (int ks = 0; ks < 2; ks++) {                                           \
        _Pragma("unroll")                                                      \
        for (int kvs = 0; kvs < 4; kvs++) {                                    \
            bf16x8 kf = *(const bf16x8*)(Ks[P] + (kvs*16 + lcol) * 64 +        \
                                         (((ks*4 + quad) ^ ksw) << 3));        \
            st[kvs] = __builtin_amdgcn_mfma_f32_16x16x32_bf16(kf, qf[ks],      \
                                                              st[kvs], 0, 0, 0); \
        }                                                                      \
    }                                                                          \
    uint32_t X[4], Y[4];                                                       \
    _Pragma("unroll")                                                          \
    for (int kvs = 0; kvs < 4; kvs++) {                                        \
        float p0 = exp2fast(st[kvs][0]), p1 = exp2fast(st[kvs][1]);            \
        float p2 = exp2fast(st[kvs][2]), p3 = exp2fast(st[kvs][3]);            \
        lp += (p0 + p1) + (p2 + p3);                                           \
        asm("v_cvt_pk_bf16_f32 %0, %1, %2" : "=v"(X[kvs]) : "v"(p0), "v"(p1)); \
        asm("v_cvt_pk_bf16_f32 %0, %1, %2" : "=v"(Y[kvs]) : "v"(p2), "v"(p3)); \
    }                                                                          \
    bf16x8 pa[2];                                                              \
    _Pragma("unroll")                                                          \
    for (int ks = 0; ks < 2; ks++) {                                           \
        uint32_t a0 = X[2*ks], a1 = X[2*ks + 1];                               \
        uint32_t b0 = Y[2*ks], b1 = Y[2*ks + 1];                               \
        asm("v_permlane16_swap_b32 %0, %1" : "+v"(a0), "+v"(a1));              \
        asm("v_permlane16_swap_b32 %0, %1" : "+v"(b0), "+v"(b1));              \
        union { uint32_t u[4]; bf16x8 v; } pk_;                                \
        pk_.u[0] = a0; pk_.u[1] = b0; pk_.u[2] = a1; pk_.u[3] = b1;            \
        pa[ks] = pk_.v;                                                        \
    }                                                                          \
    _Pragma("unroll")                                                          \
    for (int ks = 0; ks < 2; ks++) {                                           \
        _Pragma("unroll")                                                      \
        for (int tn = 0; tn < 4; tn++) {                                       \
            int row = tn * 16 + lcol;                                          \
            bf16x8 bv = *(const bf16x8*)(Vs[P] + row * 64 +                    \
                                         (((ks*4 + bq) ^ (row & 7)) << 3));    \
            o[tn] = __builtin_amdgcn_mfma_f32_16x16x32_bf16(pa[ks], bv,        \
                                                            o[tn], 0, 0, 0);   \
        }                                                                      \
    }                                                                          \
    if (WMODE == 0) { WAITCNT_VM(4); BARRIER_FENCED(); }                       \
    else if (WMODE == 1) { WAITCNT_VM(0); BARRIER_FENCED(); }                  \
} while (0)

__global__ __launch_bounds__(256)
void attn_k(const short* __restrict__ Q, const short* __restrict__ K,
            const short* __restrict__ Vt, short* __restrict__ Ab)
{
    __shared__ __align__(16) short Ks[3][4096];   // [kv][d] xor-swizzled chunks
    __shared__ __align__(16) short Vs[3][4096];   // [d][kv] xor-swizzled chunks

    const int tid = threadIdx.x, lane = tid & 63, w = tid >> 6;
    const int quad = lane >> 4, lcol = lane & 15;
    const int bid = blockIdx.x;
    const int bh = bid % 24, qt = bid / 24;
    const int b = bh / 12, h = bh - b * 12;

    const short* Kg = K  + (size_t)bh * 131072;   // [n][d] rows, tile = 8KB
    const short* Vg = Vt + (size_t)bh * 131072;   // tiled [kt][d][n64], 8KB

    bf16x8 qf[2];                       // this wave's 16 q rows only
    {
        const short* Qg = Q + ((size_t)bh * 2048 + (size_t)qt * 64) * 64;
        #pragma unroll
        for (int ks = 0; ks < 2; ks++)
            qf[ks] = *(const bf16x8*)(Qg + (w*16 + lcol) * 64 + ks*32 + quad*8);
    }

    // per-thread chunk mapping (c0: chunks 0..511, c1: 512..1023 of each tile)
    const int c0 = tid, c1 = tid + 256;
    const int r0 = c0 >> 3, s0 = r0 * 64 + (((c0 & 7) ^ (r0 & 7)) << 3);
    const int r1 = c1 >> 3, s1 = r1 * 64 + (((c1 & 7) ^ (r1 & 7)) << 3);

    // stage tiles 0,1 (4 loads/thread/tile, uniform)
    #pragma unroll
    for (int t0 = 0; t0 < 2; t0++) {
        gl_lds16(Kg + t0 * 4096 + s0, Ks[t0] + c0 * 8);
        gl_lds16(Vg + t0 * 4096 + s0, Vs[t0] + c0 * 8);
        gl_lds16(Kg + t0 * 4096 + s1, Ks[t0] + c1 * 8);
        gl_lds16(Vg + t0 * 4096 + s1, Vs[t0] + c1 * 8);
    }
    WAITCNT_VM(4);                     // Q loads + tile 0 landed; tile 1 in flight
    BARRIER_FENCED();

    // running prefetch source pointers (tile kt+2), advance 1 tile per step
    const short* pK0 = Kg + 2 * 4096 + s0;
    const short* pV0 = Vg + 2 * 4096 + s0;
    const short* pK1 = Kg + 2 * 4096 + s1;
    const short* pV1 = Vg + 2 * 4096 + s1;

    f32x4 o[4];
    #pragma unroll
    for (int tn = 0; tn < 4; tn++) o[tn] = (f32x4){0.f, 0.f, 0.f, 0.f};
    float lp = 0.f;

    const int ksw = lcol & 7;                       // K row-xor ((kvs*16+lcol)&7)
    const int bq  = ((quad & 1) << 1) | (quad >> 1); // V chunk bit-reverse perm

    for (int g = 0; g < 10; g++) {      // kt = 3g+0, 3g+1, 3g+2  (0..29)
        ATTN_STEP(0, 2, true, 0);
        ATTN_STEP(1, 0, true, 0);
        ATTN_STEP(2, 1, true, 0);
    }
    ATTN_STEP(0, 0, false, 1);          // kt = 30: drain tile 31
    ATTN_STEP(1, 0, false, 2);          // kt = 31: last, no barrier

    // row-sum: kv-split is across quads of the SAME wave -> pure shuffles
    lp += __shfl_xor(lp, 16, 64);
    lp += __shfl_xor(lp, 32, 64);
    float rl[4];
    #pragma unroll
    for (int r = 0; r < 4; r++)
        rl[r] = 1.0f / __shfl(lp, quad * 4 + r, 64);   // lane lcol=q' holds sum(q')

    #pragma unroll
    for (int tn = 0; tn < 4; tn++) {
        #pragma unroll
        for (int r = 0; r < 4; r++) {
            int q = qt * 64 + w * 16 + quad * 4 + r;
            int d = h * 64 + tn * 16 + lcol;
            Ab[((size_t)(b * 2048 + q)) * 768 + d] = f2bf(o[tn][r] * rl[r]);
        }
    }
}

// ---------------------------------------------------------------------------
// out-proj GEMM: 64x96 tiles, 512 blocks = 2/CU (grid-capped), XCD panel
// remap, 5-buffer / distance-3 / barrier-every-2, counted vmcnt.
// ---------------------------------------------------------------------------
__global__ __launch_bounds__(256)
void gemm_out(const short* __restrict__ A, const short* __restrict__ Bt,
              const float* __restrict__ bias, float* __restrict__ Of)
{
    __shared__ short As[5][64 * 32];   // 4KB per buffer (20KB)
    __shared__ short Bs[5][96 * 32];   // 6KB per buffer (30KB)
    const int tid = threadIdx.x, lane = tid & 63, w = tid >> 6;
    const int wm = w >> 1, wn = w & 1, quad = lane >> 4, lcol = lane & 15;

    // XCD-panel-grouped remap (bijective: 512 = 8 XCD * 8 bm * 8 bn)
    const int id = blockIdx.x;
    const int xcd = id & 7, j = id >> 3;
    const int bm = (xcd * 8 + (j >> 3)) * 64;
    const int bn = (j & 7) * 96;

    f32x4 acc[2][3];
    #pragma unroll
    for (int i = 0; i < 2; i++)
        #pragma unroll
        for (int jj = 0; jj < 3; jj++) acc[i][jj] = (f32x4){0.f, 0.f, 0.f, 0.f};

    const int ar0 = tid >> 2, ac0 = (tid & 3) * 8;
    const int c2  = 256 + tid;         // only tid<128 uses it
    const int br1 = c2 >> 2,  bc1 = (c2 & 3) * 8;

    const short* pA0 = A  + (size_t)(bm + ar0) * 768 + ac0;
    const short* pB0 = Bt + (size_t)(bn + ar0) * 768 + ac0;
    const short* pB1 = Bt + (size_t)(bn + br1) * 768 + bc1;

    #pragma unroll
    for (int t0 = 0; t0 < 3; t0++) {   // stage tiles 0,1,2
        const int kt = t0 * 32;
        gl_lds16(pA0 + kt, As[t0] + tid * 8);
        gl_lds16(pB0 + kt, Bs[t0] + tid * 8);
        if (tid < 128)
            gl_lds16(pB1 + kt, Bs[t0] + c2 * 8);
    }
    if (w < 2) { WAITCNT_VM(3); } else { WAITCNT_VM(2); }   // 0,1 landed; 2 in flight
    BARRIER_FENCED();

    #pragma unroll
    for (int it = 0; it < 24; it++) {
        const int p = it % 5;
        if (it < 21) {                 // prefetch tile it+3 (constants after unroll)
            const int pb = (it + 3) % 5, kt = (it + 3) * 32;
            gl_lds16(pA0 + kt, As[pb] + tid * 8);
            gl_lds16(pB0 + kt, Bs[pb] + tid * 8);
            if (tid < 128)
                gl_lds16(pB1 + kt, Bs[pb] + c2 * 8);
        }
        bf16x8 a[2], b[3];
        #pragma unroll
        for (int tm = 0; tm < 2; tm++)
            a[tm] = *(const bf16x8*)(As[p] + (wm*32 + tm*16 + lcol) * 32 + quad * 8);
        #pragma unroll
        for (int tn = 0; tn < 3; tn++)
            b[tn] = *(const bf16x8*)(Bs[p] + (wn*48 + tn*16 + lcol) * 32 + quad * 8);
        #pragma unroll
        for (int tm = 0; tm < 2; tm++)
            #pragma unroll
            for (int tn = 0; tn < 3; tn++)
                acc[tm][tn] = __builtin_amdgcn_mfma_f32_16x16x32_bf16(a[tm], b[tn], acc[tm][tn], 0, 0, 0);
        if ((it & 1) && it <= 21) {    // barrier every 2 rounds
            if (it < 21) {
                if (w < 2) { WAITCNT_VM(3); } else { WAITCNT_VM(2); }
            } else {
                WAITCNT_VM(0);         // it=21: drain tail (tiles 22,23 staged)
            }
            BARRIER_FENCED();
        }
    }
    #pragma unroll
    for (int tm = 0; tm < 2; tm++) {
        #pragma unroll
        for (int tn = 0; tn < 3; tn++) {
            int col = bn + wn*48 + tn*16 + lcol;
            float bv = bias[col];
            #pragma unroll
            for (int reg = 0; reg < 4; reg++) {
                int row = bm + wm*32 + tm*16 + quad*4 + reg;
                Of[(size_t)row * 768 + col] = acc[tm][tn][reg] + bv;
            }
        }
    }
}

// ---------------------------------------------------------------------------
extern "C" void kernel_launch(void* const* d_in, const int* in_sizes, int n_in,
                              void* d_out, int out_size, void* d_ws, size_t ws_size,
                              hipStream_t stream)
{
    (void)in_sizes; (void)n_in; (void)out_size;
    const float* x     = (const float*)d_in[0];
    const float* w_qkv = (const float*)d_in[1];
    const float* b_qkv = (const float*)d_in[2];
    const float* w_out = (const float*)d_in[3];
    const float* b_out = (const float*)d_in[4];
    float* out = (float*)d_out;

    const size_t XSZ = (size_t)4096 * 768;
    const size_t WQ  = (size_t)2304 * 768;
    const size_t WO  = (size_t)768 * 768;
    const size_t HSZ = (size_t)24 * 2048 * 64;
    short* Xb  = (short*)d_ws;
    short* Wqt = Xb + XSZ;
    short* Qb  = Wqt + WQ;
    short* Kb  = Qb + HSZ;
    short* Vt  = Kb + HSZ;
    short* Ab  = Xb;                       // x dead after gemm_qkv

    const bool sepWot = ws_size >= (XSZ + WQ + 3*HSZ + WO) * sizeof(short);
    short* Wot = sepWot ? (Vt + HSZ) : Wqt;   // else alias (w_qkv^T dead after gemm0)

    if (sepWot) {
        prep_k<<<2112, 256, 0, stream>>>(x, Xb, w_qkv, Wqt, w_out, Wot);
        gemm_qkv<<<768, 256, 0, stream>>>(Xb, Wqt, b_qkv, Qb, Kb, Vt);
    } else {
        prep_k<<<1968, 256, 0, stream>>>(x, Xb, w_qkv, Wqt, w_out, Wot);
        gemm_qkv<<<768, 256, 0, stream>>>(Xb, Wqt, b_qkv, Qb, Kb, Vt);
        tr_w<<<dim3(12, 12), 256, 0, stream>>>(w_out, Wot, 768, 768);
    }
    attn_k<<<768, 256, 0, stream>>>(Qb, Kb, Vt, Ab);
    gemm_out<<<512, 256, 0, stream>>>(Ab, Wot, b_out, out);
}

// Round 19
// 152.114 us; speedup vs baseline: 1.0270x; 1.0094x over previous
//
#include <hip/hip_runtime.h>
#include <hip/hip_bf16.h>
#include <stdint.h>

// Attention fwd: B=2, N=2048, D=768, H=12, Dh=64, INNER=768
// R30 = R22 byte-exact (measured 150.7us R10, 153.5us R18 -- confirmed
// stable best; all deltas within run noise). Final configuration:
//  * attn_k: R18-form -- compile-time 3-buffer rotation (10x3 macro steps),
//    counted vmcnt(4), in-register P transpose (cvt_pk + permlane16_swap),
//    1 barrier/iter. Latency floor: all pipes <45%, 7 structural levers
//    tested null/negative/racy.
//  * gemm_qkv: R19-form -- 128x96, 768 blocks = 3/CU (grid- and LDS-
//    matched), 3-buffer counted vmcnt, fully unrolled, XCD panel remap.
//  * gemm_out: 5-buffer / distance-3 / barrier-every-2, counted vmcnt,
//    XCD panel remap.
// Refuted: R23 wave-split (+2.0), R24 kf-prefetch (racy: vmcnt is own-wave
// only), R25 prep-fusion (+5.5), R20 A-in-regs (+19), R21 retile (+11).

typedef __attribute__((ext_vector_type(8))) short bf16x8;
typedef __attribute__((ext_vector_type(4))) float f32x4;
typedef __attribute__((address_space(3))) unsigned int lds_uint;
typedef __attribute__((address_space(1))) const unsigned int g_uint;

__device__ __forceinline__ short f2bf(float f) {
    union { float f; uint32_t u; } x; x.f = f;
    uint32_t r = (x.u + 0x7fffu + ((x.u >> 16) & 1u)) >> 16;
    return (short)r;
}
__device__ __forceinline__ float exp2fast(float x) {
#if __has_builtin(__builtin_amdgcn_exp2f)
    return __builtin_amdgcn_exp2f(x);
#else
    return __expf(x * 0.6931471805599453f);
#endif
}
__device__ __forceinline__ void gl_lds16(const void* g, void* l) {
    __builtin_amdgcn_global_load_lds((g_uint*)g, (lds_uint*)l, 16, 0, 0);
}
#define WAITCNT_VM(N) asm volatile("s_waitcnt vmcnt(" #N ")" ::: "memory")
#define BARRIER_FENCED() do { __builtin_amdgcn_s_barrier(); \
                              asm volatile("" ::: "memory"); } while (0)

// ---------------------------------------------------------------------------
// 64x64 fp32->bf16 transpose tile (shared by prep_k / tr_w)
// ---------------------------------------------------------------------------
__device__ __forceinline__ void tr_tile(const float* __restrict__ W,
                                        short* __restrict__ Wt, int K, int N,
                                        int n0, int k0, int t, short* S) {
    {
        int kl = t >> 2, ng = t & 3;
        const float* src = W + (size_t)(k0 + kl) * N + n0 + ng * 16;
        #pragma unroll
        for (int j = 0; j < 16; j += 4) {
            float4 f = *(const float4*)(src + j);
            S[(ng*16 + j + 0) * 65 + kl] = f2bf(f.x);
            S[(ng*16 + j + 1) * 65 + kl] = f2bf(f.y);
            S[(ng*16 + j + 2) * 65 + kl] = f2bf(f.z);
            S[(ng*16 + j + 3) * 65 + kl] = f2bf(f.w);
        }
    }
    __syncthreads();
    {
        int nl = t >> 2, kg = t & 3;
        short* dst = Wt + (size_t)(n0 + nl) * K + k0 + kg * 16;
        #pragma unroll
        for (int j = 0; j < 16; j += 4) {
            short4 s4;
            s4.x = S[nl*65 + kg*16 + j + 0];
            s4.y = S[nl*65 + kg*16 + j + 1];
            s4.z = S[nl*65 + kg*16 + j + 2];
            s4.w = S[nl*65 + kg*16 + j + 3];
            *(short4*)(dst + j) = s4;
        }
    }
}

// fused prep: [0,1536) x->bf16 ; [1536,1968) w_qkv^T ; [1968,2112) w_out^T
__global__ __launch_bounds__(256)
void prep_k(const float* __restrict__ x, short* __restrict__ Xb,
            const float* __restrict__ Wq, short* __restrict__ Wqt,
            const float* __restrict__ Wo, short* __restrict__ Wot)
{
    __shared__ short S[64 * 65];
    const int t = threadIdx.x;
    if (blockIdx.x < 1536) {
        int i = (blockIdx.x * 256 + t) * 8;
        float4 f0 = *(const float4*)(x + i);
        float4 f1 = *(const float4*)(x + i + 4);
        short s[8];
        s[0]=f2bf(f0.x); s[1]=f2bf(f0.y); s[2]=f2bf(f0.z); s[3]=f2bf(f0.w);
        s[4]=f2bf(f1.x); s[5]=f2bf(f1.y); s[6]=f2bf(f1.z); s[7]=f2bf(f1.w);
        *(uint4*)(Xb + i) = *(uint4*)s;
        return;
    }
    if (blockIdx.x < 1968) {
        const int b2 = blockIdx.x - 1536;                  // N=2304, K=768
        tr_tile(Wq, Wqt, 768, 2304, (b2 % 36) * 64, (b2 / 36) * 64, t, S);
    } else {
        const int b3 = blockIdx.x - 1968;                  // N=768, K=768
        tr_tile(Wo, Wot, 768, 768, (b3 % 12) * 64, (b3 / 12) * 64, t, S);
    }
}

// standalone w_out transpose (fallback when Wot must alias Wqt)
__global__ __launch_bounds__(256)
void tr_w(const float* __restrict__ W, short* __restrict__ Wt, int K, int N) {
    __shared__ short S[64 * 65];
    tr_tile(W, Wt, K, N, blockIdx.x * 64, blockIdx.y * 64, threadIdx.x, S);
}

// ---------------------------------------------------------------------------
// QKV GEMM: 128x96 tiles, 768 blocks = 3/CU, triple-buffered counted-vmcnt
// staging, fully unrolled K-loop, XCD panel remap
// (768 = 8 xcd x 4 bm x 24 bn; per-XCD A 0.77MB + B 3.5MB, L2-resident).
// [4096x768]bf16 @ Wqt[2304x768]^T + b -> Qb(pre-scaled)/Kb/Vt bf16
// ---------------------------------------------------------------------------
__global__ __launch_bounds__(256)
void gemm_qkv(const short* __restrict__ A, const short* __restrict__ Bt,
              const float* __restrict__ bias,
              short* __restrict__ Qb, short* __restrict__ Kb, short* __restrict__ Vt)
{
    __shared__ short As[3][128 * 32];  // 512 chunks of 16B per buffer (24KB)
    __shared__ short Bs[3][96 * 32];   // 384 chunks per buffer (18KB)
    const int tid = threadIdx.x, lane = tid & 63, w = tid >> 6;
    const int wm = w >> 1, wn = w & 1, quad = lane >> 4, lcol = lane & 15;

    // XCD-panel-grouped remap (bijective: 768 = 8 XCD * 4 bm * 24 bn)
    const int id = blockIdx.x;
    const int xcd = id & 7, j = id >> 3;
    const int bm = (xcd * 4 + (j / 24)) * 128;
    const int bn = (j % 24) * 96;

    f32x4 acc[4][3];
    #pragma unroll
    for (int i = 0; i < 4; i++)
        #pragma unroll
        for (int jj = 0; jj < 3; jj++) acc[i][jj] = (f32x4){0.f, 0.f, 0.f, 0.f};

    const int ar0 = tid >> 2,         ac0 = (tid & 3) * 8;
    const int ar1 = (tid + 256) >> 2;
    const int c2  = 256 + tid;         // only tid<128 uses it
    const int br1 = c2 >> 2,          bc1 = (c2 & 3) * 8;

    const short* pA0 = A  + (size_t)(bm + ar0) * 768 + ac0;
    const short* pA1 = A  + (size_t)(bm + ar1) * 768 + ac0;
    const short* pB0 = Bt + (size_t)(bn + ar0) * 768 + ac0;
    const short* pB1 = Bt + (size_t)(bn + br1) * 768 + bc1;

    #pragma unroll
    for (int t0 = 0; t0 < 2; t0++) {   // stage tiles 0,1
        const int kt = t0 * 32;
        gl_lds16(pA0 + kt, As[t0] + tid * 8);
        gl_lds16(pA1 + kt, As[t0] + (tid + 256) * 8);
        gl_lds16(pB0 + kt, Bs[t0] + tid * 8);
        if (tid < 128)
            gl_lds16(pB1 + kt, Bs[t0] + c2 * 8);
    }
    if (w < 2) { WAITCNT_VM(4); } else { WAITCNT_VM(3); }   // tile0 done, tile1 in flight
    BARRIER_FENCED();

    #pragma unroll
    for (int it = 0; it < 24; it++) {
        const int p = it % 3;
        if (it < 22) {                 // prefetch tile it+2 (constants after unroll)
            const int pb = (it + 2) % 3, kt = (it + 2) * 32;
            gl_lds16(pA0 + kt, As[pb] + tid * 8);
            gl_lds16(pA1 + kt, As[pb] + (tid + 256) * 8);
            gl_lds16(pB0 + kt, Bs[pb] + tid * 8);
            if (tid < 128)
                gl_lds16(pB1 + kt, Bs[pb] + c2 * 8);
        }
        bf16x8 a[4], b[3];
        #pragma unroll
        for (int tm = 0; tm < 4; tm++)
            a[tm] = *(const bf16x8*)(As[p] + (wm*64 + tm*16 + lcol) * 32 + quad * 8);
        #pragma unroll
        for (int tn = 0; tn < 3; tn++)
            b[tn] = *(const bf16x8*)(Bs[p] + (wn*48 + tn*16 + lcol) * 32 + quad * 8);
        #pragma unroll
        for (int tm = 0; tm < 4; tm++)
            #pragma unroll
            for (int tn = 0; tn < 3; tn++)
                acc[tm][tn] = __builtin_amdgcn_mfma_f32_16x16x32_bf16(a[tm], b[tn], acc[tm][tn], 0, 0, 0);
        if (it < 23) {
            if (it < 22) {             // tile it+1 landed, it+2 stays in flight
                if (w < 2) { WAITCNT_VM(4); } else { WAITCNT_VM(3); }
            } else {
                WAITCNT_VM(0);         // drain last staged tile
            }
            BARRIER_FENCED();
        }
    }

    const float SCLQ = 0.18033688011112042f;   // 0.125 * log2(e) folded into Q
    #pragma unroll
    for (int tm = 0; tm < 4; tm++) {
        #pragma unroll
        for (int tn = 0; tn < 3; tn++) {
            int col = bn + wn*48 + tn*16 + lcol;
            float bv = bias[col];
            int which = (col >= 1536) ? 2 : (col >= 768 ? 1 : 0);
            int cc = col - which * 768;
            int h = cc >> 6, d = cc & 63;
            int rowbase = bm + wm*64 + tm*16 + quad*4;
            int bb = rowbase >> 11, n0 = rowbase & 2047;
            int bh = bb * 12 + h;
            if (which == 2) {                 // V: tiled V^T store, dense window
                short4 s4;
                s4.x = f2bf(acc[tm][tn][0] + bv);
                s4.y = f2bf(acc[tm][tn][1] + bv);
                s4.z = f2bf(acc[tm][tn][2] + bv);
                s4.w = f2bf(acc[tm][tn][3] + bv);
                *(short4*)(Vt + (((size_t)bh*32 + (n0 >> 6))*64 + d)*64 + (n0 & 63)) = s4;
            } else {
                #pragma unroll
                for (int reg = 0; reg < 4; reg++) {
                    float v = acc[tm][tn][reg] + bv;
                    if (which == 0) v *= SCLQ;
                    short* dst = (which == 0) ? Qb : Kb;
                    dst[((size_t)bh*2048 + n0 + reg)*64 + d] = f2bf(v);
                }
            }
        }
    }
}

// ---------------------------------------------------------------------------
// Flash attention: R15 compute, compile-time buffer rotation via 10x3
// macro-unrolled steps, 4 running DMA pointers.
// WMODE: 0 = vmcnt(4)+barrier (steady), 1 = vmcnt(0)+barrier, 2 = none.
// ---------------------------------------------------------------------------
#define ATTN_STEP(P, PB, DO_PRE, WMODE) do {                                   \
    if (DO_PRE) {                                                              \
        gl_lds16(pK0, Ks[PB] + c0 * 8);                                        \
        gl_lds16(pV0, Vs[PB] + c0 * 8);                                        \
        gl_lds16(pK1, Ks[PB] + c1 * 8);                                        \
        gl_lds16(pV1, Vs[PB] + c1 * 8);                                        \
        pK0 += 4096; pV0 += 4096; pK1 += 4096; pV1 += 4096;                    \
    }                                                                          \
    f32x4 st[4];                                                               \
    _Pragma("unroll")                                                          \
    for (int kvs = 0; kvs < 4; kvs++) st[kvs] = (f32x4){0.f, 0.f, 0.f, 0.f};   \
    _Pragma("unroll")                                                          \
    for (int ks = 0; ks < 2; ks++) {                                           \
        _Pragma("unroll")                                                      \
        for (int kvs = 0; kvs < 4; kvs++) {                                    \
            bf16x8 kf = *(const bf16x8*)(Ks[P] + (kvs*16 + lcol) * 64 +        \
                                         (((ks*4 + quad) ^ ksw) << 3));        \
            st[kvs] = __builtin_amdgcn_mfma_f32_16x16x32_bf16(kf, qf[ks],      \
                                                              st[kvs], 0, 0, 0); \
        }                                                                      \
    }                                                                          \
    uint32_t X[4], Y[4];                                                       \
    _Pragma("unroll")                                                          \
    for (int kvs = 0; kvs < 4; kvs++) {                                        \
        float p0 = exp2fast(st[kvs][0]), p1 = exp2fast(st[kvs][1]);            \
        float p2 = exp2fast(st[kvs][2]), p3 = exp2fast(st[kvs][3]);            \
        lp += (p0 + p1) + (p2 + p3);                                           \
        asm("v_cvt_pk_bf16_f32 %0, %1, %2" : "=v"(X[kvs]) : "v"(p0), "v"(p1)); \
        asm("v_cvt_pk_bf16_f32 %0, %1, %2" : "=v"(Y[kvs]) : "v"(p2), "v"(p3)); \
    }                                                                          \
    bf16x8 pa[2];                                                              \
    _Pragma("unroll")                                                          \
    for (int ks = 0; ks < 2; ks++) {                                           \
        uint32_t a0 = X[2*ks], a1 = X[2*ks + 1];                               \
        uint32_t b0 = Y[2*ks], b1 = Y[2*ks + 1];                               \
        asm("v_permlane16_swap_b32 %0, %1" : "+v"(a0), "+v"(a1));              \
        asm("v_permlane16_swap_b32 %0, %1" : "+v"(b0), "+v"(b1));              \
        union { uint32_t u[4]; bf16x8 v; } pk_;                                \
        pk_.u[0] = a0; pk_.u[1] = b0; pk_.u[2] = a1; pk_.u[3] = b1;            \
        pa[ks] = pk_.v;                                                        \
    }                                                                          \
    _Pragma("unroll")                                                          \
    for (int ks = 0; ks < 2; ks++) {                                           \
        _Pragma("unroll")                                                      \
        for (int tn = 0; tn < 4; tn++) {                                       \
            int row = tn * 16 + lcol;                                          \
            bf16x8 bv = *(const bf16x8*)(Vs[P] + row * 64 +                    \
                                         (((ks*4 + bq) ^ (row & 7)) << 3));    \
            o[tn] = __builtin_amdgcn_mfma_f32_16x16x32_bf16(pa[ks], bv,        \
                                                            o[tn], 0, 0, 0);   \
        }                                                                      \
    }                                                                          \
    if (WMODE == 0) { WAITCNT_VM(4); BARRIER_FENCED(); }                       \
    else if (WMODE == 1) { WAITCNT_VM(0); BARRIER_FENCED(); }                  \
} while (0)

__global__ __launch_bounds__(256)
void attn_k(const short* __restrict__ Q, const short* __restrict__ K,
            const short* __restrict__ Vt, short* __restrict__ Ab)
{
    __shared__ __align__(16) short Ks[3][4096];   // [kv][d] xor-swizzled chunks
    __shared__ __align__(16) short Vs[3][4096];   // [d][kv] xor-swizzled chunks

    const int tid = threadIdx.x, lane = tid & 63, w = tid >> 6;
    const int quad = lane >> 4, lcol = lane & 15;
    const int bid = blockIdx.x;
    const int bh = bid % 24, qt = bid / 24;
    const int b = bh / 12, h = bh - b * 12;

    const short* Kg = K  + (size_t)bh * 131072;   // [n][d] rows, tile = 8KB
    const short* Vg = Vt + (size_t)bh * 131072;   // tiled [kt][d][n64], 8KB

    bf16x8 qf[2];                       // this wave's 16 q rows only
    {
        const short* Qg = Q + ((size_t)bh * 2048 + (size_t)qt * 64) * 64;
        #pragma unroll
        for (int ks = 0; ks < 2; ks++)
            qf[ks] = *(const bf16x8*)(Qg + (w*16 + lcol) * 64 + ks*32 + quad*8);
    }

    // per-thread chunk mapping (c0: chunks 0..511, c1: 512..1023 of each tile)
    const int c0 = tid, c1 = tid + 256;
    const int r0 = c0 >> 3, s0 = r0 * 64 + (((c0 & 7) ^ (r0 & 7)) << 3);
    const int r1 = c1 >> 3, s1 = r1 * 64 + (((c1 & 7) ^ (r1 & 7)) << 3);

    // stage tiles 0,1 (4 loads/thread/tile, uniform)
    #pragma unroll
    for (int t0 = 0; t0 < 2; t0++) {
        gl_lds16(Kg + t0 * 4096 + s0, Ks[t0] + c0 * 8);
        gl_lds16(Vg + t0 * 4096 + s0, Vs[t0] + c0 * 8);
        gl_lds16(Kg + t0 * 4096 + s1, Ks[t0] + c1 * 8);
        gl_lds16(Vg + t0 * 4096 + s1, Vs[t0] + c1 * 8);
    }
    WAITCNT_VM(4);                     // Q loads + tile 0 landed; tile 1 in flight
    BARRIER_FENCED();

    // running prefetch source pointers (tile kt+2), advance 1 tile per step
    const short* pK0 = Kg + 2 * 4096 + s0;
    const short* pV0 = Vg + 2 * 4096 + s0;
    const short* pK1 = Kg + 2 * 4096 + s1;
    const short* pV1 = Vg + 2 * 4096 + s1;

    f32x4 o[4];
    #pragma unroll
    for (int tn = 0; tn < 4; tn++) o[tn] = (f32x4){0.f, 0.f, 0.f, 0.f};
    float lp = 0.f;

    const int ksw = lcol & 7;                       // K row-xor ((kvs*16+lcol)&7)
    const int bq  = ((quad & 1) << 1) | (quad >> 1); // V chunk bit-reverse perm

    for (int g = 0; g < 10; g++) {      // kt = 3g+0, 3g+1, 3g+2  (0..29)
        ATTN_STEP(0, 2, true, 0);
        ATTN_STEP(1, 0, true, 0);
        ATTN_STEP(2, 1, true, 0);
    }
    ATTN_STEP(0, 0, false, 1);          // kt = 30: drain tile 31
    ATTN_STEP(1, 0, false, 2);          // kt = 31: last, no barrier

    // row-sum: kv-split is across quads of the SAME wave -> pure shuffles
    lp += __shfl_xor(lp, 16, 64);
    lp += __shfl_xor(lp, 32, 64);
    float rl[4];
    #pragma unroll
    for (int r = 0; r < 4; r++)
        rl[r] = 1.0f / __shfl(lp, quad * 4 + r, 64);   // lane lcol=q' holds sum(q')

    #pragma unroll
    for (int tn = 0; tn < 4; tn++) {
        #pragma unroll
        for (int r = 0; r < 4; r++) {
            int q = qt * 64 + w * 16 + quad * 4 + r;
            int d = h * 64 + tn * 16 + lcol;
            Ab[((size_t)(b * 2048 + q)) * 768 + d] = f2bf(o[tn][r] * rl[r]);
        }
    }
}

// ---------------------------------------------------------------------------
// out-proj GEMM: 64x96 tiles, 512 blocks = 2/CU (grid-capped), XCD panel
// remap, 5-buffer / distance-3 / barrier-every-2, counted vmcnt.
// ---------------------------------------------------------------------------
__global__ __launch_bounds__(256)
void gemm_out(const short* __restrict__ A, const short* __restrict__ Bt,
              const float* __restrict__ bias, float* __restrict__ Of)
{
    __shared__ short As[5][64 * 32];   // 4KB per buffer (20KB)
    __shared__ short Bs[5][96 * 32];   // 6KB per buffer (30KB)
    const int tid = threadIdx.x, lane = tid & 63, w = tid >> 6;
    const int wm = w >> 1, wn = w & 1, quad = lane >> 4, lcol = lane & 15;

    // XCD-panel-grouped remap (bijective: 512 = 8 XCD * 8 bm * 8 bn)
    const int id = blockIdx.x;
    const int xcd = id & 7, j = id >> 3;
    const int bm = (xcd * 8 + (j >> 3)) * 64;
    const int bn = (j & 7) * 96;

    f32x4 acc[2][3];
    #pragma unroll
    for (int i = 0; i < 2; i++)
        #pragma unroll
        for (int jj = 0; jj < 3; jj++) acc[i][jj] = (f32x4){0.f, 0.f, 0.f, 0.f};

    const int ar0 = tid >> 2, ac0 = (tid & 3) * 8;
    const int c2  = 256 + tid;         // only tid<128 uses it
    const int br1 = c2 >> 2,  bc1 = (c2 & 3) * 8;

    const short* pA0 = A  + (size_t)(bm + ar0) * 768 + ac0;
    const short* pB0 = Bt + (size_t)(bn + ar0) * 768 + ac0;
    const short* pB1 = Bt + (size_t)(bn + br1) * 768 + bc1;

    #pragma unroll
    for (int t0 = 0; t0 < 3; t0++) {   // stage tiles 0,1,2
        const int kt = t0 * 32;
        gl_lds16(pA0 + kt, As[t0] + tid * 8);
        gl_lds16(pB0 + kt, Bs[t0] + tid * 8);
        if (tid < 128)
            gl_lds16(pB1 + kt, Bs[t0] + c2 * 8);
    }
    if (w < 2) { WAITCNT_VM(3); } else { WAITCNT_VM(2); }   // 0,1 landed; 2 in flight
    BARRIER_FENCED();

    #pragma unroll
    for (int it = 0; it < 24; it++) {
        const int p = it % 5;
        if (it < 21) {                 // prefetch tile it+3 (constants after unroll)
            const int pb = (it + 3) % 5, kt = (it + 3) * 32;
            gl_lds16(pA0 + kt, As[pb] + tid * 8);
            gl_lds16(pB0 + kt, Bs[pb] + tid * 8);
            if (tid < 128)
                gl_lds16(pB1 + kt, Bs[pb] + c2 * 8);
        }
        bf16x8 a[2], b[3];
        #pragma unroll
        for (int tm = 0; tm < 2; tm++)
            a[tm] = *(const bf16x8*)(As[p] + (wm*32 + tm*16 + lcol) * 32 + quad * 8);
        #pragma unroll
        for (int tn = 0; tn < 3; tn++)
            b[tn] = *(const bf16x8*)(Bs[p] + (wn*48 + tn*16 + lcol) * 32 + quad * 8);
        #pragma unroll
        for (int tm = 0; tm < 2; tm++)
            #pragma unroll
            for (int tn = 0; tn < 3; tn++)
                acc[tm][tn] = __builtin_amdgcn_mfma_f32_16x16x32_bf16(a[tm], b[tn], acc[tm][tn], 0, 0, 0);
        if ((it & 1) && it <= 21) {    // barrier every 2 rounds
            if (it < 21) {
                if (w < 2) { WAITCNT_VM(3); } else { WAITCNT_VM(2); }
            } else {
                WAITCNT_VM(0);         // it=21: drain tail (tiles 22,23 staged)
            }
            BARRIER_FENCED();
        }
    }
    #pragma unroll
    for (int tm = 0; tm < 2; tm++) {
        #pragma unroll
        for (int tn = 0; tn < 3; tn++) {
            int col = bn + wn*48 + tn*16 + lcol;
            float bv = bias[col];
            #pragma unroll
            for (int reg = 0; reg < 4; reg++) {
                int row = bm + wm*32 + tm*16 + quad*4 + reg;
                Of[(size_t)row * 768 + col] = acc[tm][tn][reg] + bv;
            }
        }
    }
}

// ---------------------------------------------------------------------------
extern "C" void kernel_launch(void* const* d_in, const int* in_sizes, int n_in,
                              void* d_out, int out_size, void* d_ws, size_t ws_size,
                              hipStream_t stream)
{
    (void)in_sizes; (void)n_in; (void)out_size;
    const float* x     = (const float*)d_in[0];
    const float* w_qkv = (const float*)d_in[1];
    const float* b_qkv = (const float*)d_in[2];
    const float* w_out = (const float*)d_in[3];
    const float* b_out = (const float*)d_in[4];
    float* out = (float*)d_out;

    const size_t XSZ = (size_t)4096 * 768;
    const size_t WQ  = (size_t)2304 * 768;
    const size_t WO  = (size_t)768 * 768;
    const size_t HSZ = (size_t)24 * 2048 * 64;
    short* Xb  = (short*)d_ws;
    short* Wqt = Xb + XSZ;
    short* Qb  = Wqt + WQ;
    short* Kb  = Qb + HSZ;
    short* Vt  = Kb + HSZ;
    short* Ab  = Xb;                       // x dead after gemm_qkv

    const bool sepWot = ws_size >= (XSZ + WQ + 3*HSZ + WO) * sizeof(short);
    short* Wot = sepWot ? (Vt + HSZ) : Wqt;   // else alias (w_qkv^T dead after gemm0)

    if (sepWot) {
        prep_k<<<2112, 256, 0, stream>>>(x, Xb, w_qkv, Wqt, w_out, Wot);
        gemm_qkv<<<768, 256, 0, stream>>>(Xb, Wqt, b_qkv, Qb, Kb, Vt);
    } else {
        prep_k<<<1968, 256, 0, stream>>>(x, Xb, w_qkv, Wqt, w_out, Wot);
        gemm_qkv<<<768, 256, 0, stream>>>(Xb, Wqt, b_qkv, Qb, Kb, Vt);
        tr_w<<<dim3(12, 12), 256, 0, stream>>>(w_out, Wot, 768, 768);
    }
    attn_k<<<768, 256, 0, stream>>>(Qb, Kb, Vt, Ab);
    gemm_out<<<512, 256, 0, stream>>>(Ab, Wot, b_out, out);
}